// Round 7
// baseline (494.058 us; speedup 1.0000x reference)
//
#include <hip/hip_runtime.h>

typedef unsigned short u16;
typedef __attribute__((ext_vector_type(8))) unsigned short u16x8;
typedef __bf16 bf16x8 __attribute__((ext_vector_type(8)));
typedef float f32x4 __attribute__((ext_vector_type(4)));

__device__ __forceinline__ u16 f2b(float f) {
    unsigned u = __float_as_uint(f);
    u += 0x7fffu + ((u >> 16) & 1u);   // RNE bf16 (finite values only)
    return (u16)(u >> 16);
}
__device__ __forceinline__ float b2f(u16 h) {
    return __uint_as_float(((unsigned)h) << 16);
}

__device__ __forceinline__ void async_copy16(const void* g, void* l) {
    __builtin_amdgcn_global_load_lds(
        (const __attribute__((address_space(1))) unsigned int*)g,
        (__attribute__((address_space(3))) unsigned int*)l,
        16, 0, 0);
}

// Bank-spread swizzle for [row][128B] tiles read as 16B chunks:
// byte ^= ((row&7)<<4). Involution (bits [6:4] keyed by bits [9:7]).
__device__ __forceinline__ int swz(int x) { return x ^ (((x >> 7) & 7) << 4); }

// ---------------- cast f32 -> bf16, 8 elems/thread ----------------
__global__ __launch_bounds__(256) void cast_kernel(const float* __restrict__ in,
                                                   u16* __restrict__ out, long n) {
    long i0 = ((long)blockIdx.x * 256 + threadIdx.x) * 8;
    long stride = (long)gridDim.x * 256 * 8;
    for (long i = i0; i < n; i += stride) {
        float4 a = *(const float4*)(in + i);
        float4 b = *(const float4*)(in + i + 4);
        u16x8 o;
        o[0] = f2b(a.x); o[1] = f2b(a.y); o[2] = f2b(a.z); o[3] = f2b(a.w);
        o[4] = f2b(b.x); o[5] = f2b(b.y); o[6] = f2b(b.z); o[7] = f2b(b.w);
        *(u16x8*)(out + i) = o;
    }
}

// ---------------- fused 3-weight cast ----------------
__global__ __launch_bounds__(256) void cast3_kernel(const float* __restrict__ w0,
                                                    const float* __restrict__ w1,
                                                    const float* __restrict__ w2,
                                                    u16* __restrict__ o0,
                                                    u16* __restrict__ o1,
                                                    u16* __restrict__ o2, long n) {
    int z = blockIdx.z;
    const float* in = (z == 0) ? w0 : (z == 1) ? w1 : w2;
    u16* out = (z == 0) ? o0 : (z == 1) ? o1 : o2;
    long i = ((long)blockIdx.x * 256 + threadIdx.x) * 8;
    if (i < n) {
        float4 a = *(const float4*)(in + i);
        float4 b = *(const float4*)(in + i + 4);
        u16x8 o;
        o[0] = f2b(a.x); o[1] = f2b(a.y); o[2] = f2b(a.z); o[3] = f2b(a.w);
        o[4] = f2b(b.x); o[5] = f2b(b.y); o[6] = f2b(b.z); o[7] = f2b(b.w);
        *(u16x8*)(out + i) = o;
    }
}

// ---------------- zero fp32 buffer ----------------
__global__ __launch_bounds__(256) void zero_kernel(float* __restrict__ p, long n4) {
    long i = (long)blockIdx.x * 256 + threadIdx.x;
    if (i < n4) ((float4*)p)[i] = float4{0.f, 0.f, 0.f, 0.f};
}

// ---------------- bf16 transpose, 64x64 tiles, vectorized both sides -------
__global__ __launch_bounds__(256) void transpose_kernel(const u16* __restrict__ in,
                                                        u16* __restrict__ out,
                                                        int S_, int D_) {
    __shared__ u16 tile[64 * 64];
    long base = (long)blockIdx.z * (long)S_ * D_;
    int r0 = blockIdx.y * 64;   // s
    int c0 = blockIdx.x * 64;   // d
    int t = threadIdx.x;
    {
        int r = t >> 3, cb = (t & 7) * 16;   // byte col
        #pragma unroll
        for (int h = 0; h < 2; ++h) {
            int rr = r + h * 32;
            u16x8 d8 = *(const u16x8*)(in + base + (long)(r0 + rr) * D_ + c0 + (cb >> 1));
            int phys = rr * 128 + (cb ^ (((rr >> 3) & 7) << 4));
            *(u16x8*)((char*)tile + phys) = d8;
        }
    }
    __syncthreads();
    {
        int od = t & 63;
        int gb = (t >> 6) * 2;
        #pragma unroll
        for (int h = 0; h < 2; ++h) {
            int g = gb + h;
            u16x8 o8;
            #pragma unroll
            for (int j = 0; j < 8; ++j) {
                int rr = g * 8 + j;
                int phys = rr * 128 + ((od * 2) ^ (((rr >> 3) & 7) << 4));
                o8[j] = *(const u16*)((char*)tile + phys);
            }
            *(u16x8*)(out + base + (long)(c0 + od) * S_ + r0 + g * 8) = o8;
        }
    }
}

// ---------------- 256x256 8-phase bf16 BT-GEMM (QV / out-proj) ----------------
// MODE 0 (QV): 512 blocks; xcd=id&7 groups 8 (bn,z) sharing one x-row-panel.
// MODE 1 (OUT): 256 blocks; xcd groups 4 bn sharing one ctx-panel. fp32 out.
template<int MODE, typename OUTT>
__global__ __launch_bounds__(512)
void gemm_u(const u16* __restrict__ Aall, const u16* __restrict__ Ball,
            const float* __restrict__ bias, const float* __restrict__ bias2,
            OUTT* __restrict__ Call,
            int N, int K, long sB, long sC) {
    const int id = blockIdx.x;
    int bm, bn, z = 0;
    if constexpr (MODE == 0) {
        int xcd = id & 7, s = id >> 3;
        z = s >> 5; bm = xcd + 8 * ((s >> 2) & 7); bn = s & 3;
    } else {
        int xcd = id & 7, s = id >> 3;
        bm = xcd + 8 * (s >> 2); bn = s & 3;
    }
    const u16* A = Aall;
    const u16* B = Ball + (long)z * sB;
    OUTT* C = Call + (long)z * sC;
    const float* bp = z ? bias2 : bias;
    const int NT = K >> 6;

    extern __shared__ __align__(16) char lds[];

    const int tid = threadIdx.x;
    const int lane = tid & 63;
    const int w = tid >> 6;
    const int wm = w >> 2, wn = w & 3;
    const int fr = lane & 15, hi = lane >> 4;
    const int axor = (fr & 7) << 4;

    const long rowA0 = (long)bm * 256;
    const long rowB0 = (long)bn * 256;

    auto stage_half = [&](const u16* mat, long gr0, int k0, char* region) {
        #pragma unroll
        for (int rd = 0; rd < 2; ++rd) {
            int pb = rd * 8192 + w * 1024;
            int p = pb + lane * 16;
            int Lb = swz(p);
            const u16* src = mat + (gr0 + (Lb >> 7)) * (long)K + k0 + ((Lb & 127) >> 1);
            async_copy16(src, region + pb);
        }
    };

    f32x4 acc[8][4] = {};
    bf16x8 a[4][2], b0[2][2], b1[2][2];

    char* bufp0 = lds;
    char* bufp1 = lds + 65536;

    stage_half(A, rowA0,       0, bufp0 + 0 * 16384);
    stage_half(B, rowB0,       0, bufp0 + 2 * 16384);
    stage_half(B, rowB0 + 128, 0, bufp0 + 3 * 16384);
    stage_half(A, rowA0 + 128, 0, bufp0 + 1 * 16384);
    asm volatile("s_waitcnt vmcnt(4)" ::: "memory");
    if (1 < NT) {
        stage_half(A, rowA0,       64, bufp1 + 0 * 16384);
        stage_half(B, rowB0,       64, bufp1 + 2 * 16384);
        stage_half(B, rowB0 + 128, 64, bufp1 + 3 * 16384);
    }
    asm volatile("s_waitcnt vmcnt(6)" ::: "memory");
    __builtin_amdgcn_s_barrier();

    const int abase = (wm * 64 + fr) * 128 + hi * 16;
    const int bbase = (wn * 32 + fr) * 128 + hi * 16;

    for (int u = 0; u < NT; ++u) {
        char* bufp  = (u & 1) ? bufp1 : bufp0;
        char* obufp = (u & 1) ? bufp0 : bufp1;

        // ===== phase 1: read A-lo + B-lo; stage A1(u+1) =====
        #pragma unroll
        for (int m = 0; m < 4; ++m)
            #pragma unroll
            for (int kk = 0; kk < 2; ++kk)
                a[m][kk] = *(const bf16x8*)(bufp + 0 * 16384 + ((abase + m * 2048 + kk * 64) ^ axor));
        #pragma unroll
        for (int nl = 0; nl < 2; ++nl)
            #pragma unroll
            for (int kk = 0; kk < 2; ++kk)
                b0[nl][kk] = *(const bf16x8*)(bufp + 2 * 16384 + ((bbase + nl * 2048 + kk * 64) ^ axor));
        if (u + 1 < NT)
            stage_half(A, rowA0 + 128, (u + 1) * 64, obufp + 1 * 16384);
        asm volatile("s_waitcnt lgkmcnt(8)" ::: "memory");
        __builtin_amdgcn_s_barrier();
        asm volatile("s_waitcnt lgkmcnt(0)" ::: "memory");
        __builtin_amdgcn_sched_barrier(0);
        __builtin_amdgcn_s_setprio(1);
        #pragma unroll
        for (int m = 0; m < 4; ++m)
            #pragma unroll
            for (int nl = 0; nl < 2; ++nl)
                #pragma unroll
                for (int kk = 0; kk < 2; ++kk)
                    acc[m][nl] = __builtin_amdgcn_mfma_f32_16x16x32_bf16(a[m][kk], b0[nl][kk], acc[m][nl], 0, 0, 0);
        __builtin_amdgcn_s_setprio(0);
        __builtin_amdgcn_s_barrier();

        // ===== phase 2: read B-hi; stage A0(u+2) =====
        #pragma unroll
        for (int nl = 0; nl < 2; ++nl)
            #pragma unroll
            for (int kk = 0; kk < 2; ++kk)
                b1[nl][kk] = *(const bf16x8*)(bufp + 3 * 16384 + ((bbase + nl * 2048 + kk * 64) ^ axor));
        if (u + 2 < NT)
            stage_half(A, rowA0, (u + 2) * 64, bufp + 0 * 16384);
        __builtin_amdgcn_s_barrier();
        asm volatile("s_waitcnt lgkmcnt(0)" ::: "memory");
        __builtin_amdgcn_sched_barrier(0);
        __builtin_amdgcn_s_setprio(1);
        #pragma unroll
        for (int m = 0; m < 4; ++m)
            #pragma unroll
            for (int nl = 0; nl < 2; ++nl)
                #pragma unroll
                for (int kk = 0; kk < 2; ++kk)
                    acc[m][2 + nl] = __builtin_amdgcn_mfma_f32_16x16x32_bf16(a[m][kk], b1[nl][kk], acc[m][2 + nl], 0, 0, 0);
        __builtin_amdgcn_s_setprio(0);
        __builtin_amdgcn_s_barrier();

        // ===== phase 3: read A-hi; stage B0(u+2) =====
        #pragma unroll
        for (int m = 0; m < 4; ++m)
            #pragma unroll
            for (int kk = 0; kk < 2; ++kk)
                a[m][kk] = *(const bf16x8*)(bufp + 1 * 16384 + ((abase + m * 2048 + kk * 64) ^ axor));
        if (u + 2 < NT)
            stage_half(B, rowB0, (u + 2) * 64, bufp + 2 * 16384);
        __builtin_amdgcn_s_barrier();
        asm volatile("s_waitcnt lgkmcnt(0)" ::: "memory");
        __builtin_amdgcn_sched_barrier(0);
        __builtin_amdgcn_s_setprio(1);
        #pragma unroll
        for (int m = 0; m < 4; ++m)
            #pragma unroll
            for (int nl = 0; nl < 2; ++nl)
                #pragma unroll
                for (int kk = 0; kk < 2; ++kk)
                    acc[4 + m][2 + nl] = __builtin_amdgcn_mfma_f32_16x16x32_bf16(a[m][kk], b1[nl][kk], acc[4 + m][2 + nl], 0, 0, 0);
        __builtin_amdgcn_s_setprio(0);
        __builtin_amdgcn_s_barrier();

        // ===== phase 4: stage B1(u+2); counted vmcnt =====
        if (u + 2 < NT)
            stage_half(B, rowB0 + 128, (u + 2) * 64, bufp + 3 * 16384);
        __builtin_amdgcn_s_barrier();
        __builtin_amdgcn_s_setprio(1);
        #pragma unroll
        for (int m = 0; m < 4; ++m)
            #pragma unroll
            for (int nl = 0; nl < 2; ++nl)
                #pragma unroll
                for (int kk = 0; kk < 2; ++kk)
                    acc[4 + m][nl] = __builtin_amdgcn_mfma_f32_16x16x32_bf16(a[m][kk], b0[nl][kk], acc[4 + m][nl], 0, 0, 0);
        __builtin_amdgcn_s_setprio(0);
        if (u < NT - 2) { asm volatile("s_waitcnt vmcnt(6)" ::: "memory"); }
        else            { asm volatile("s_waitcnt vmcnt(0)" ::: "memory"); }
        __builtin_amdgcn_s_barrier();
    }

    // ---- epilogue ----
    #pragma unroll
    for (int m = 0; m < 8; ++m) {
        int rl = (m < 4) ? (wm * 64 + m * 16) : (128 + wm * 64 + (m - 4) * 16);
        long grow = rowA0 + rl + hi * 4;
        #pragma unroll
        for (int n = 0; n < 4; ++n) {
            int cl = (n < 2) ? (wn * 32 + n * 16) : (128 + wn * 32 + (n - 2) * 16);
            long gcol = rowB0 + cl + fr;
            float bvv = bp[gcol];
            #pragma unroll
            for (int j = 0; j < 4; ++j) {
                float v = acc[m][n][j] + bvv;
                if constexpr (sizeof(OUTT) == 2) {
                    C[(grow + j) * N + gcol] = (OUTT)f2b(v);
                } else {
                    C[(grow + j) * N + gcol] = v;
                }
            }
        }
    }
}

// ---------------- 256x128 2-phase-per-Ktile bf16 BT-GEMM (scores / PV) -----
// Same discipline as gemm_u: per phase {ds_read || stage || barrier ||
// lgkmcnt(0) || 16 MFMA || counted vmcnt(6)}. LDS 96KB = 2 bufs x
// {Alo,Ahi,B} x 16KB. 8 waves 2Mx4N; wave owns 128 rows x 32 cols.
// MODE 2 (SCORES): 576 blocks; bz=id&7; t=id>>3 -> (bm, col-half h).
//   Epilogue: E=exp(acc/32) causal-masked, bf16 store + rowsum atomicAdd.
// MODE 3 (PV): 256 blocks; bz=id&7; s=id>>3: p=s&3, bn=s>>2. Two tiles:
//   bm=p and bm=7-p (uniform 9 K-units). Epilogue: divide by rowsum.
template<int MODE>
__global__ __launch_bounds__(512)
void gemm_h(const u16* __restrict__ Aall, const u16* __restrict__ Ball,
            u16* __restrict__ Call, float* __restrict__ rowsum,
            int N, int K, float scale, long sA, long sB, long sC) {
    extern __shared__ __align__(16) char lds[];
    const int tid = threadIdx.x;
    const int lane = tid & 63;
    const int w = tid >> 6;
    const int wm = w >> 2, wn = w & 3;
    const int fr = lane & 15, hi = lane >> 4;
    const int axor = (fr & 7) << 4;
    const int abase = (wm * 64 + fr) * 128 + hi * 16;
    const int bbase = (wn * 32 + fr) * 128 + hi * 16;

    const int bz = blockIdx.x & 7;
    const u16* A = Aall + (long)bz * sA;
    const u16* B = Ball + (long)bz * sB;
    u16* C = Call + (long)bz * sC;
    float* rsv = rowsum + bz * 2048;

    auto run_tile = [&](long rowA0, long colB0, int NT, bool domask) {
        auto stage = [&](const u16* mat, long gr0, int k0, char* region) {
            #pragma unroll
            for (int rd = 0; rd < 2; ++rd) {
                int pb = rd * 8192 + w * 1024;
                int pp = pb + lane * 16;
                int Lb = swz(pp);
                const u16* src = mat + (gr0 + (Lb >> 7)) * (long)K + k0 + ((Lb & 127) >> 1);
                async_copy16(src, region + pb);
            }
        };
        char* bf0 = lds;             // regions: Alo@0, Ahi@16384, B@32768
        char* bf1 = lds + 49152;
        f32x4 acc[8][2] = {};
        bf16x8 a[4][2], bb[2][2];

        // prologue: Alo0,B0,Ahi0 -> bf0 ; Alo1,B1 -> bf1
        stage(A, rowA0,       0, bf0 + 0);
        stage(B, colB0,       0, bf0 + 32768);
        stage(A, rowA0 + 128, 0, bf0 + 16384);
        if (1 < NT) {
            stage(A, rowA0, 64, bf1 + 0);
            stage(B, colB0, 64, bf1 + 32768);
        }
        asm volatile("s_waitcnt vmcnt(6)" ::: "memory");
        __builtin_amdgcn_s_barrier();

        for (int u = 0; u < NT; ++u) {
            char* cb = (u & 1) ? bf1 : bf0;
            char* ob = (u & 1) ? bf0 : bf1;

            // ===== phase 1: read A-lo + B; stage A-hi(u+1) -> ob =====
            #pragma unroll
            for (int m = 0; m < 4; ++m)
                #pragma unroll
                for (int kk = 0; kk < 2; ++kk)
                    a[m][kk] = *(const bf16x8*)(cb + ((abase + m * 2048 + kk * 64) ^ axor));
            #pragma unroll
            for (int nl = 0; nl < 2; ++nl)
                #pragma unroll
                for (int kk = 0; kk < 2; ++kk)
                    bb[nl][kk] = *(const bf16x8*)(cb + 32768 + ((bbase + nl * 2048 + kk * 64) ^ axor));
            if (u + 1 < NT)
                stage(A, rowA0 + 128, (u + 1) * 64, ob + 16384);
            asm volatile("s_waitcnt lgkmcnt(8)" ::: "memory");
            __builtin_amdgcn_s_barrier();
            asm volatile("s_waitcnt lgkmcnt(0)" ::: "memory");
            __builtin_amdgcn_sched_barrier(0);
            __builtin_amdgcn_s_setprio(1);
            #pragma unroll
            for (int m = 0; m < 4; ++m)
                #pragma unroll
                for (int nl = 0; nl < 2; ++nl)
                    #pragma unroll
                    for (int kk = 0; kk < 2; ++kk)
                        acc[m][nl] = __builtin_amdgcn_mfma_f32_16x16x32_bf16(a[m][kk], bb[nl][kk], acc[m][nl], 0, 0, 0);
            __builtin_amdgcn_s_setprio(0);
            if (u < NT - 1) { asm volatile("s_waitcnt vmcnt(6)" ::: "memory"); }
            else            { asm volatile("s_waitcnt vmcnt(0)" ::: "memory"); }
            __builtin_amdgcn_s_barrier();

            // ===== phase 2: read A-hi; stage A-lo(u+2), B(u+2) -> cb =====
            #pragma unroll
            for (int m = 0; m < 4; ++m)
                #pragma unroll
                for (int kk = 0; kk < 2; ++kk)
                    a[m][kk] = *(const bf16x8*)(cb + 16384 + ((abase + m * 2048 + kk * 64) ^ axor));
            if (u + 2 < NT) {
                stage(A, rowA0, (u + 2) * 64, cb + 0);
                stage(B, colB0, (u + 2) * 64, cb + 32768);
            }
            __builtin_amdgcn_s_barrier();
            asm volatile("s_waitcnt lgkmcnt(0)" ::: "memory");
            __builtin_amdgcn_sched_barrier(0);
            __builtin_amdgcn_s_setprio(1);
            #pragma unroll
            for (int m = 0; m < 4; ++m)
                #pragma unroll
                for (int nl = 0; nl < 2; ++nl)
                    #pragma unroll
                    for (int kk = 0; kk < 2; ++kk)
                        acc[4 + m][nl] = __builtin_amdgcn_mfma_f32_16x16x32_bf16(a[m][kk], bb[nl][kk], acc[4 + m][nl], 0, 0, 0);
            __builtin_amdgcn_s_setprio(0);
            if (u < NT - 2) { asm volatile("s_waitcnt vmcnt(6)" ::: "memory"); }
            else            { asm volatile("s_waitcnt vmcnt(0)" ::: "memory"); }
            __builtin_amdgcn_s_barrier();
        }

        // ---- epilogue ----
        #pragma unroll
        for (int m = 0; m < 8; ++m) {
            int rl = (m < 4) ? (wm * 64 + m * 16) : (128 + wm * 64 + (m - 4) * 16);
            long grow = rowA0 + rl + hi * 4;
            if constexpr (MODE == 2) {
                float rs_acc[4] = {0.f, 0.f, 0.f, 0.f};
                #pragma unroll
                for (int n = 0; n < 2; ++n) {
                    long gcol = colB0 + wn * 32 + n * 16 + fr;
                    #pragma unroll
                    for (int j = 0; j < 4; ++j) {
                        long r = grow + j;
                        float e = (!domask || gcol <= r) ? __expf(acc[m][n][j] * scale) : 0.f;
                        u16 wv = f2b(e);
                        C[r * N + gcol] = wv;
                        rs_acc[j] += b2f(wv);
                    }
                }
                #pragma unroll
                for (int j = 0; j < 4; ++j) {
                    float v = rs_acc[j];
                    v += __shfl_xor(v, 1); v += __shfl_xor(v, 2);
                    v += __shfl_xor(v, 4); v += __shfl_xor(v, 8);
                    if (fr == 0) atomicAdd(&rsv[(int)(grow + j)], v);
                }
            } else {
                float inv[4];
                #pragma unroll
                for (int j = 0; j < 4; ++j) inv[j] = 1.0f / rsv[(int)(grow + j)];
                #pragma unroll
                for (int n = 0; n < 2; ++n) {
                    long gcol = colB0 + wn * 32 + n * 16 + fr;
                    #pragma unroll
                    for (int j = 0; j < 4; ++j)
                        C[(grow + j) * N + gcol] = f2b(acc[m][n][j] * inv[j]);
                }
            }
        }
    };

    if constexpr (MODE == 2) {
        int t = blockIdx.x >> 3;            // 0..71
        int bm = 0;
        #pragma unroll
        for (int c = 1; c < 8; ++c)
            if (t >= c * c + c) bm = c;
        int h = t - (bm * bm + bm);         // 0..2bm+1
        run_tile((long)bm * 256, (long)h * 128, K >> 6, h >= 2 * bm);
    } else {
        int s = blockIdx.x >> 3;
        int p = s & 3, bn = s >> 2;         // bn 0..7 over D
        #pragma unroll
        for (int r = 0; r < 2; ++r) {
            int bm = r ? (7 - p) : p;
            run_tile((long)bm * 256, (long)bn * 128, (bm + 1) * 4, false);
        }
    }
}

extern "C" void kernel_launch(void* const* d_in, const int* in_sizes, int n_in,
                              void* d_out, int out_size, void* d_ws, size_t ws_size,
                              hipStream_t stream) {
    (void)in_sizes; (void)n_in; (void)out_size; (void)ws_size;
    const float* x  = (const float*)d_in[0];
    // d_in[1] = mask (deterministic tril) - handled analytically
    const float* Wq = (const float*)d_in[2];
    const float* bq = (const float*)d_in[3];
    // d_in[4], d_in[5] = Wk, bk : dead code in reference
    const float* Wv = (const float*)d_in[6];
    const float* bv = (const float*)d_in[7];
    const float* Wo = (const float*)d_in[8];
    const float* bo = (const float*)d_in[9];
    float* out = (float*)d_out;

    const long B = 8, S = 2048, D = 1024;
    const long MS = B * S;                 // 16384

    char* p = (char*)d_ws;
    u16* xb  = (u16*)p; p += MS * D * 2;   // reused as ctxb later
    u16* Wqb = (u16*)p; p += D * D * 2;    // Wqb/Wvb adjacent (sB = D*D)
    u16* Wvb = (u16*)p; p += D * D * 2;
    u16* Wob = (u16*)p; p += D * D * 2;
    u16* Qb  = (u16*)p; p += MS * D * 2;   // Qb/Vb adjacent (sC = MS*D)
    u16* Vb  = (u16*)p; p += MS * D * 2;
    u16* Sb  = (u16*)p; p += B * S * S * 2;
    float* rowsum = (float*)p; p += MS * 4;
    u16* ctxb = xb;
    u16* Vtb  = Qb;

    const int SMEM = 131072, SMEMH = 98304;
    (void)hipFuncSetAttribute((const void*)gemm_u<0, u16>,
                              hipFuncAttributeMaxDynamicSharedMemorySize, SMEM);
    (void)hipFuncSetAttribute((const void*)gemm_u<1, float>,
                              hipFuncAttributeMaxDynamicSharedMemorySize, SMEM);
    (void)hipFuncSetAttribute((const void*)gemm_h<2>,
                              hipFuncAttributeMaxDynamicSharedMemorySize, SMEMH);
    (void)hipFuncSetAttribute((const void*)gemm_h<3>,
                              hipFuncAttributeMaxDynamicSharedMemorySize, SMEMH);

    // 1. casts + rowsum zero
    cast_kernel<<<4096, 256, 0, stream>>>(x, xb, MS * D);
    cast3_kernel<<<dim3(512, 1, 3), 256, 0, stream>>>(Wq, Wv, Wo, Wqb, Wvb, Wob, D * D);
    zero_kernel<<<16, 256, 0, stream>>>(rowsum, MS / 4);

    // 2. fused Q+V projections — 512 blocks, XCD groups share x-panels
    gemm_u<0, u16><<<512, 512, SMEM, stream>>>(
        xb, Wqb, bq, bv, Qb, (int)D, (int)D, D * D, MS * D);

    // 3. scores: E = exp(Q*V^T/32) causal + rowsum atomics — 576 half-tiles
    gemm_h<2><<<576, 512, SMEMH, stream>>>(
        Qb, Vb, Sb, rowsum, (int)S, (int)D, 0.03125f, S * D, S * D, S * S);

    // 4. V^T (aliases Qb; Q dead after scores)
    dim3 gtr(D / 64, S / 64, B);
    transpose_kernel<<<gtr, 256, 0, stream>>>(Vb, Vtb, (int)S, (int)D);

    // 5. ctx = (E * V) / rowsum — paired causal bm, uniform 9 K-units/block
    gemm_h<3><<<256, 512, SMEMH, stream>>>(
        Sb, Vtb, ctxb, rowsum, (int)D, (int)S, 1.0f, S * S, D * S, S * D);

    // 6. out = ctx*Wo^T + bo (fp32 out)
    gemm_u<1, float><<<256, 512, SMEM, stream>>>(
        ctxb, Wob, bo, nullptr, out, (int)D, (int)D, 0, 0);
}